// Round 3
// baseline (513.726 us; speedup 1.0000x reference)
//
#include <hip/hip_runtime.h>
#include <hip/hip_bf16.h>

#define EPS_F 1e-12f

typedef __attribute__((ext_vector_type(8))) short bf16x8;
typedef __attribute__((ext_vector_type(4))) float f32x4;

__device__ __forceinline__ unsigned short f2bf(float f) {
    __hip_bfloat16 h = __float2bfloat16(f);
    unsigned short u; __builtin_memcpy(&u, &h, 2); return u;
}

// ---------------------------------------------------------------------------
// Sizes: N=32, H=W=64 -> P=131072 (4096/sample), D=512, K=116 (pad KP=128)
// Inputs fp32; MFMA in bf16 (convert at staging); OUTPUT fp32 (reference dtype).
// ws layout (bytes):
//   At   @ 0         : 32*128*4096*2 = 33,554,432   bf16  (n,k,p)
//   ax0  @ 33554432  : 32*512*128*4  =  8,388,608   f32   (n,d,kpad)
//   ax1  @ 41943040  :                 8,388,608
//   asum @ 50331648  : 32*128*4      =     16,384   f32 (zeroed)
//   ss   @ 50348032  : 32*128*4      =     16,384   f32 (zeroed)
//   scl  @ 50364416  : 32*128*4      =     16,384   f32
//   WT   @ 50380800  : 128*512*2     =    131,072   bf16  (k,d)
// total ~50.5 MB (earlier rounds prove ws_size >= this)
// ---------------------------------------------------------------------------

__global__ void wt_prep(const float* __restrict__ w,
                        unsigned short* __restrict__ WT) {
    int id = blockIdx.x * 256 + threadIdx.x;   // 65536 = 128*512
    int k = id >> 9, d = id & 511;
    WT[k * 512 + d] = (k < 116) ? f2bf(w[d * 116 + k]) : (unsigned short)0;
}

// GEMM s = x*W (tile 256px x 128k), fused masked softmax over k, asum atomics,
// LDS-transposed store of a -> At (n,k,p) bf16.
__global__ __launch_bounds__(256, 2)
void assign_k(const float* __restrict__ x,
              const unsigned short* __restrict__ WT,
              unsigned short* __restrict__ At,
              float* __restrict__ asum) {
    __shared__ unsigned short sm[27648];          // 55,296 B
    unsigned short* Xs = sm;                      // 256 x 72
    unsigned short* Ws = sm + 18432;              // 128 x 72
    const int tid = threadIdx.x;
    const int wave = tid >> 6, lane = tid & 63;
    const int quad = lane >> 4, l15 = lane & 15;
    const int pxbase = blockIdx.x * 256;
    const int n = pxbase >> 12;

    f32x4 acc[4][8];
#pragma unroll
    for (int s = 0; s < 4; ++s)
#pragma unroll
        for (int c = 0; c < 8; ++c) acc[s][c] = (f32x4){0.f, 0.f, 0.f, 0.f};

    for (int dch = 0; dch < 8; ++dch) {
        const int dof = dch * 64;
#pragma unroll
        for (int it = 0; it < 16; ++it) {         // stage X: 256px x 64d (f32->bf16)
            int cid = it * 256 + tid;             // 0..4095
            int r = cid >> 4, co = (cid & 15) * 4;
            float4 v = *(const float4*)(x + (size_t)(pxbase + r) * 512 + dof + co);
            ushort4 u;
            u.x = f2bf(v.x); u.y = f2bf(v.y); u.z = f2bf(v.z); u.w = f2bf(v.w);
            *(ushort4*)(Xs + r * 72 + co) = u;
        }
#pragma unroll
        for (int i = 0; i < 4; ++i) {             // stage W^T: 128k x 64d (bf16)
            int cid = i * 256 + tid;
            int r = cid >> 3, co = (cid & 7) * 8;
            uint4 v = *(const uint4*)(WT + r * 512 + dof + co);
            *(uint4*)(Ws + r * 72 + co) = v;
        }
        __syncthreads();
#pragma unroll
        for (int ks = 0; ks < 2; ++ks) {
            const int ko = ks * 32 + quad * 8;
            bf16x8 af[4], bfr[8];
#pragma unroll
            for (int s = 0; s < 4; ++s)
                af[s] = *(const bf16x8*)(Xs + (wave * 64 + s * 16 + l15) * 72 + ko);
#pragma unroll
            for (int c = 0; c < 8; ++c)
                bfr[c] = *(const bf16x8*)(Ws + (c * 16 + l15) * 72 + ko);
#pragma unroll
            for (int s = 0; s < 4; ++s)
#pragma unroll
                for (int c = 0; c < 8; ++c)
                    acc[s][c] = __builtin_amdgcn_mfma_f32_16x16x32_bf16(
                        af[s], bfr[c], acc[s][c], 0, 0, 0);
        }
        __syncthreads();
    }

    // masked softmax over k (cols c*16+l15; only c==7 has invalid cols >=116)
    const bool v7 = (l15 < 4);
#pragma unroll
    for (int s = 0; s < 4; ++s) {
#pragma unroll
        for (int r = 0; r < 4; ++r) {
            float mx = acc[s][0][r];
#pragma unroll
            for (int c = 1; c < 7; ++c) mx = fmaxf(mx, acc[s][c][r]);
            if (v7) mx = fmaxf(mx, acc[s][7][r]);
#pragma unroll
            for (int off = 1; off < 16; off <<= 1) mx = fmaxf(mx, __shfl_xor(mx, off));
            float sum = 0.f;
#pragma unroll
            for (int c = 0; c < 8; ++c) {
                float e = (c < 7 || v7) ? __expf(acc[s][c][r] - mx) : 0.f;
                acc[s][c][r] = e; sum += e;
            }
#pragma unroll
            for (int off = 1; off < 16; off <<= 1) sum += __shfl_xor(sum, off);
            float inv = 1.0f / sum;
#pragma unroll
            for (int c = 0; c < 8; ++c) acc[s][c][r] *= inv;
        }
    }

    // asum: column sums over this wave's 64 px, reduce across quads, atomic
#pragma unroll
    for (int c = 0; c < 8; ++c) {
        float cs = 0.f;
#pragma unroll
        for (int s = 0; s < 4; ++s)
#pragma unroll
            for (int r = 0; r < 4; ++r) cs += acc[s][c][r];
        cs += __shfl_xor(cs, 16);
        cs += __shfl_xor(cs, 32);
        int k = c * 16 + l15;
        if (lane < 16 && k < 116) atomicAdd(asum + n * 128 + k, cs);
    }

    // LDS transpose -> At (n,k,p), two 64-col batches, per-wave buffer
    __syncthreads();
    unsigned short* tb = sm + wave * 4608;        // 64 x 72
    const int pw = (pxbase & 4095) + wave * 64;
#pragma unroll
    for (int ch = 0; ch < 2; ++ch) {
#pragma unroll
        for (int c4 = 0; c4 < 4; ++c4) {
            int c = ch * 4 + c4;
            int kk = c4 * 16 + l15;
#pragma unroll
            for (int s = 0; s < 4; ++s) {
                ushort4 u;
                u.x = f2bf(acc[s][c][0]); u.y = f2bf(acc[s][c][1]);
                u.z = f2bf(acc[s][c][2]); u.w = f2bf(acc[s][c][3]);
                *(ushort4*)(tb + kk * 72 + s * 16 + quad * 4) = u;
            }
        }
        // wave-local: DS ops in order, no barrier needed
#pragma unroll
        for (int it = 0; it < 8; ++it) {
            int id = it * 64 + lane;
            int row = id >> 3, chk = id & 7;
            uint4 v = *(const uint4*)(tb + row * 72 + chk * 8);
            *(uint4*)(At + (size_t)(n * 128 + ch * 64 + row) * 4096 + pw + chk * 8) = v;
        }
    }
}

// ax^T[k,d] = At(n,k,p) * x(n,p,d); block = 128k x 64d, p-split 2 -> ax0/ax1.
// blockIdx swizzled so same-(n,ps) dblk siblings share an XCD L2.
__global__ __launch_bounds__(256, 2)
void ax_k(const float* __restrict__ x,
          const unsigned short* __restrict__ At,
          float* __restrict__ ax0, float* __restrict__ ax1) {
    __shared__ unsigned short sm[13824];          // 27,648 B
    unsigned short* Ats = sm;                     // 128 x 72
    unsigned short* Xts = sm + 9216;              // 64(d) x 72(p)
    const int tid = threadIdx.x;
    const int wave = tid >> 6, lane = tid & 63;
    const int quad = lane >> 4, l15 = lane & 15;
    const int bid = blockIdx.x;
    const int xcd = bid & 7, slot = bid >> 3;
    const int dblk = slot & 7, ghi = slot >> 3;
    const int g = ghi * 8 + xcd;                  // 0..63
    const int n = g >> 1, ps = g & 1;
    const int dbase = dblk * 64;
    const int p0 = ps * 2048;

    f32x4 acc[2][4];
#pragma unroll
    for (int s = 0; s < 2; ++s)
#pragma unroll
        for (int c = 0; c < 4; ++c) acc[s][c] = (f32x4){0.f, 0.f, 0.f, 0.f};

    for (int pc = 0; pc < 32; ++pc) {
        const int pb = p0 + pc * 64;
#pragma unroll
        for (int i = 0; i < 4; ++i) {             // stage At: 128k x 64p (bf16)
            int cid = i * 256 + tid;
            int r = cid >> 3, co = (cid & 7) * 8;
            uint4 v = *(const uint4*)(At + (size_t)(n * 128 + r) * 4096 + pb + co);
            *(uint4*)(Ats + r * 72 + co) = v;
        }
        {                                         // stage x transposed: Xts[d][p], f32->bf16
            const float* xrow = x + (size_t)(n * 4096 + pb + lane) * 512 + dbase + wave * 16;
#pragma unroll
            for (int f = 0; f < 4; ++f) {
                float4 v = *(const float4*)(xrow + f * 4);
                int dl = wave * 16 + f * 4;
                Xts[(dl + 0) * 72 + lane] = f2bf(v.x);
                Xts[(dl + 1) * 72 + lane] = f2bf(v.y);
                Xts[(dl + 2) * 72 + lane] = f2bf(v.z);
                Xts[(dl + 3) * 72 + lane] = f2bf(v.w);
            }
        }
        __syncthreads();
#pragma unroll
        for (int ks = 0; ks < 2; ++ks) {
            const int ko = ks * 32 + quad * 8;
            bf16x8 af[2], bfr[4];
            af[0] = *(const bf16x8*)(Ats + (wave * 32 + l15) * 72 + ko);
            af[1] = *(const bf16x8*)(Ats + (wave * 32 + 16 + l15) * 72 + ko);
#pragma unroll
            for (int c = 0; c < 4; ++c)
                bfr[c] = *(const bf16x8*)(Xts + (c * 16 + l15) * 72 + ko);
#pragma unroll
            for (int s = 0; s < 2; ++s)
#pragma unroll
                for (int c = 0; c < 4; ++c)
                    acc[s][c] = __builtin_amdgcn_mfma_f32_16x16x32_bf16(
                        af[s], bfr[c], acc[s][c], 0, 0, 0);
        }
        __syncthreads();
    }

    float* axp = ps ? ax1 : ax0;                  // ax (n, d, kpad128) f32
#pragma unroll
    for (int s = 0; s < 2; ++s)
#pragma unroll
        for (int c = 0; c < 4; ++c) {
            int d = dbase + c * 16 + l15;
            int k = wave * 32 + s * 16 + quad * 4;
            *(f32x4*)(axp + (size_t)(n * 512 + d) * 128 + k) = acc[s][c];
        }
}

// per-(n,k) sum over d of v^2, v = ax0+ax1+C*asum ; partial over 64 d + atomic
__global__ void ss_k(const float* __restrict__ ax0, const float* __restrict__ ax1,
                     const float* __restrict__ C,
                     const float* __restrict__ asum, float* __restrict__ ssb) {
    __shared__ float red[256];
    const int tid = threadIdx.x;
    const int n = blockIdx.x >> 3, dgrp = blockIdx.x & 7;
    const int k = tid & 127, dh = tid >> 7;
    const float as = asum[n * 128 + k];
    float ssq = 0.f;
    for (int i = 0; i < 32; ++i) {
        int d = dgrp * 64 + i * 2 + dh;
        size_t ix = (size_t)(n * 512 + d) * 128 + k;
        float cc = (k < 116) ? C[d * 116 + k] : 0.f;
        float v = ax0[ix] + ax1[ix] + cc * as;
        ssq += v * v;
    }
    red[tid] = ssq;
    __syncthreads();
    if (dh == 0) atomicAdd(ssb + n * 128 + k, red[tid] + red[tid + 128]);
}

// combined scale = rsqrt(ss+eps) * rsqrt(sum_k ss/(ss+eps) + eps)
__global__ void scale_k(const float* __restrict__ ssb, float* __restrict__ scl) {
    __shared__ float red[128];
    const int n = blockIdx.x, k = threadIdx.x;
    const float s = ssb[n * 128 + k];
    red[k] = (k < 116) ? (s / (s + EPS_F)) : 0.f;
    __syncthreads();
    for (int off = 64; off > 0; off >>= 1) {
        if (k < off) red[k] += red[k + off];
        __syncthreads();
    }
    float rowinv = rsqrtf(red[0] + EPS_F);
    scl[n * 128 + k] = rsqrtf(s + EPS_F) * rowinv;
}

// out[n, d*116+k] = (ax0+ax1+C*asum) * scale, fp32 (reference output dtype)
__global__ void emit_k(const float* __restrict__ ax0, const float* __restrict__ ax1,
                       const float* __restrict__ C,
                       const float* __restrict__ asum, const float* __restrict__ scl,
                       float* __restrict__ out) {
    const int n = blockIdx.x >> 3, dgrp = blockIdx.x & 7;
    const int tid = threadIdx.x;
    for (int i = 0; i < 29; ++i) {                // 29*256 = 7424 = 64*116
        int idx = i * 256 + tid;
        int dl = idx / 116;
        int k = idx - dl * 116;
        int d = dgrp * 64 + dl;
        size_t ix = (size_t)(n * 512 + d) * 128 + k;
        float v = ax0[ix] + ax1[ix] + C[d * 116 + k] * asum[n * 128 + k];
        out[(size_t)n * 59392 + dgrp * 7424 + idx] = v * scl[n * 128 + k];
    }
}

extern "C" void kernel_launch(void* const* d_in, const int* in_sizes, int n_in,
                              void* d_out, int out_size, void* d_ws, size_t ws_size,
                              hipStream_t stream) {
    const float* x = (const float*)d_in[0];   // (32,64,64,512) f32
    const float* w = (const float*)d_in[1];   // (512,116) f32
    const float* C = (const float*)d_in[2];   // (512,116) f32
    float* out = (float*)d_out;               // (32, 59392) f32

    char* ws = (char*)d_ws;
    unsigned short* At  = (unsigned short*)ws;
    float* ax0  = (float*)(ws + 33554432);
    float* ax1  = (float*)(ws + 41943040);
    float* asum = (float*)(ws + 50331648);
    float* ssb  = (float*)(ws + 50348032);
    float* scl  = (float*)(ws + 50364416);
    unsigned short* WT = (unsigned short*)(ws + 50380800);

    // zero asum + ss (contiguous 32 KiB); ws is re-poisoned before every call
    hipMemsetAsync(ws + 50331648, 0, 32768, stream);

    wt_prep <<<256, 256, 0, stream>>>(w, WT);
    assign_k<<<512, 256, 0, stream>>>(x, WT, At, asum);
    ax_k    <<<512, 256, 0, stream>>>(x, At, ax0, ax1);
    ss_k    <<<256, 256, 0, stream>>>(ax0, ax1, C, asum, ssb);
    scale_k <<<32, 128, 0, stream>>>(ssb, scl);
    emit_k  <<<256, 256, 0, stream>>>(ax0, ax1, C, asum, scl, out);
}